// Round 3
// baseline (175.253 us; speedup 1.0000x reference)
//
#include <hip/hip_runtime.h>

#define HH 128
#define WW 128
#define NPIX (HH*WW)
#define NC 35
#define CAP 4096           // list capacity per (b,label); mean occupancy ~470, 170 sigma margin
#define NCHUNK 64          // chunks of 64 pixels per bucket covered by gemm grid

// ---------------- Kernel 1: transpose x -> xt (pixel-major, +conv scalar), argmax, bucket build
__global__ __launch_bounds__(256) void prep_kernel(
    const float* __restrict__ x, const float* __restrict__ layout,
    const float* __restrict__ pr, const float* __restrict__ cw,
    const float* __restrict__ cb, const float* __restrict__ pl,
    float* __restrict__ xt, int* __restrict__ cnt, int* __restrict__ list)
{
    __shared__ float s_t[64*65];   // [c][p] stride 65
    __shared__ float s_s[64];

    const int t  = threadIdx.x;
    const int bk = blockIdx.x;           // 512: b(2) x ptile(256)
    const int b  = bk >> 8;
    const int p0 = (bk & 255) << 6;      // 64-pixel aligned run, same h
    const int h  = p0 >> 7;
    const int w0 = p0 & 127;

    // stage x tile (64c x 64p) into LDS, fully coalesced float4
    const float4* x4 = (const float4*)x + (size_t)b*64*4096 + (p0 >> 2);
    #pragma unroll
    for (int k = 0; k < 4; ++k) {
        int f = k*256 + t;
        int c = f >> 4, i = f & 15;
        float4 q = x4[c*4096 + i];
        int base = c*65 + i*4;
        s_t[base+0]=q.x; s_t[base+1]=q.y; s_t[base+2]=q.z; s_t[base+3]=q.w;
    }

    if (t < 64) {
        // conv scalar s for pixel p0+t
        int w = w0 + t;
        float pxv = (float)h * (2.0f/128.0f) - 1.0f;
        float pyv = (float)w * (2.0f/128.0f) - 1.0f;
        float pl0 = pl[h*WW + w];
        float pl1 = pl[NPIX + h*WW + w];
        float pr0 = pr[((b*2+0)*HH + h)*WW + w];
        float pr1 = pr[((b*2+1)*HH + h)*WW + w];
        int kx = w % 3, kyy = h % 3;
        const float C1 = -0.5f, S1 = 0.86602540378443864676f;
        float xcv = (kx==0)  ? 1.0f : C1;
        float xsv = (kx==0)  ? 0.0f : ((kx==1)  ? S1 : -S1);
        float ycv = (kyy==0) ? 1.0f : C1;
        float ysv = (kyy==0) ? 0.0f : ((kyy==1) ? S1 : -S1);
        s_s[t] = cb[0] + pxv*cw[0] + pyv*cw[1] + pl0*cw[2] + pl1*cw[3]
               + pr0*cw[4] + pr1*cw[5] + xcv*cw[6] + xsv*cw[7]
               + ycv*cw[8] + ysv*cw[9];
    } else if (t < 128) {
        // argmax over 35 layout channels for pixel p0+lane (first-max = strict >)
        int lane = t - 64;
        const float* lp = layout + (size_t)(b*NC)*NPIX + p0 + lane;
        float best = lp[0]; int bi = 0;
        #pragma unroll
        for (int c = 1; c < NC; ++c) {
            float v = lp[(size_t)c*NPIX];
            if (v > best) { best = v; bi = c; }
        }
        int idx = atomicAdd(&cnt[b*NC + bi], 1);
        if (idx < CAP) list[(b*NC + bi)*CAP + idx] = p0 + lane;
    }
    __syncthreads();

    // write xt[b][p][c] = x + s, coalesced 1KB/instr
    float4* xt4 = (float4*)xt + ((size_t)b*NPIX + p0)*16;
    #pragma unroll
    for (int k = 0; k < 4; ++k) {
        int g = k*256 + t;
        int p = g >> 4, c4 = g & 15;
        float sp = s_s[p];
        float4 q;
        q.x = s_t[(c4*4+0)*65 + p] + sp;
        q.y = s_t[(c4*4+1)*65 + p] + sp;
        q.z = s_t[(c4*4+2)*65 + p] + sp;
        q.w = s_t[(c4*4+3)*65 + p] + sp;
        xt4[p*16 + c4] = q;
    }
}

// ---------------- Kernel 2: bucketed matvec. One block per (b,label,chunk of 64 px).
// W_l column held in 64 VGPRs per lane (lane = o). x rows broadcast from LDS.
__global__ __launch_bounds__(256) void gemm_kernel(
    const float* __restrict__ Wt, const float* __restrict__ bt,
    const float* __restrict__ xt, const int* __restrict__ cnt,
    const int* __restrict__ list, float* __restrict__ yt,
    float* __restrict__ sums)
{
    const int bk    = blockIdx.x;            // 2*35*NCHUNK
    const int chunk = bk & (NCHUNK-1);
    const int bl    = bk >> 6;               // b*35 + l
    const int n     = cnt[bl];
    const int base  = chunk * 64;
    if (base >= n) return;
    const int m = min(64, n - base);
    const int b = bl / NC, l = bl % NC;

    __shared__ float s_x[64*64];             // [p][c]
    __shared__ int   s_pix[64];
    __shared__ float s_red[4][64][2];

    const int t = threadIdx.x;
    const int wv = t >> 6, lane = t & 63;

    if (t < 64) s_pix[t] = (t < m) ? list[bl*CAP + base + t] : 0;
    __syncthreads();

    // gather xt rows (256B contiguous each) into LDS
    {
        int p = t >> 2, j = t & 3;
        if (p < m) {
            const float4* r = (const float4*)xt + ((size_t)b*NPIX + s_pix[p])*16;
            #pragma unroll
            for (int k = 0; k < 4; ++k)
                *((float4*)(s_x + p*64 + j*16 + k*4)) = r[j*4 + k];
        }
    }

    // W_l column for this lane -> 64 VGPRs (64 coalesced 256B loads, L2-hot)
    float Wcol[64];
    const float* Wl = Wt + l*4096 + lane;
    #pragma unroll
    for (int c = 0; c < 64; ++c) Wcol[c] = Wl[c*64];
    float bias = bt[l*64 + lane];
    __syncthreads();

    float ssum = 0.f, sss = 0.f;
    #pragma unroll 1
    for (int i = 0; i < 16; ++i) {
        int p = wv*16 + i;                   // wave-uniform -> scalar branch
        if (p < m) {
            float acc = bias;
            const float4* xr = (const float4*)(s_x + p*64);
            #pragma unroll
            for (int c4 = 0; c4 < 16; ++c4) {
                float4 xq = xr[c4];          // all-lane same-address broadcast
                acc = fmaf(xq.x, Wcol[4*c4+0], acc);
                acc = fmaf(xq.y, Wcol[4*c4+1], acc);
                acc = fmaf(xq.z, Wcol[4*c4+2], acc);
                acc = fmaf(xq.w, Wcol[4*c4+3], acc);
            }
            yt[((size_t)b*NPIX + s_pix[p])*64 + lane] = acc;  // 256B coalesced
            ssum += acc; sss += acc*acc;
        }
    }
    s_red[wv][lane][0] = ssum;
    s_red[wv][lane][1] = sss;
    __syncthreads();
    if (wv == 0) {
        float S  = s_red[0][lane][0]+s_red[1][lane][0]+s_red[2][lane][0]+s_red[3][lane][0];
        float SS = s_red[0][lane][1]+s_red[1][lane][1]+s_red[2][lane][1]+s_red[3][lane][1];
        atomicAdd(&sums[(b*64+lane)*2+0], S);
        atomicAdd(&sums[(b*64+lane)*2+1], SS);
    }
}

// ---------------- Kernel 3: transpose yt -> out with instance-norm + leaky fused
__global__ __launch_bounds__(256) void norm_kernel(
    const float* __restrict__ yt, const float* __restrict__ sums,
    float* __restrict__ out)
{
    __shared__ float s_t[64*65];   // [o][p] stride 65
    __shared__ float s_mean[64], s_rstd[64];

    const int t  = threadIdx.x;
    const int bk = blockIdx.x;           // 512: b x ptile
    const int b  = bk >> 8;
    const int p0 = (bk & 255) << 6;

    if (t < 64) {
        float S  = sums[(b*64+t)*2+0];
        float SS = sums[(b*64+t)*2+1];
        const float invN = 1.0f/16384.0f;
        float mean = S * invN;
        float var  = SS * invN - mean*mean;
        s_mean[t] = mean;
        s_rstd[t] = rsqrtf(var + 1e-5f);
    }

    const float4* y4 = (const float4*)yt + ((size_t)b*NPIX + p0)*16;
    #pragma unroll
    for (int k = 0; k < 4; ++k) {
        int g = k*256 + t;
        int p = g >> 4, o4 = g & 15;
        float4 q = y4[p*16 + o4];
        int base = (o4*4)*65 + p;
        s_t[base]     = q.x;
        s_t[base+65]  = q.y;
        s_t[base+130] = q.z;
        s_t[base+195] = q.w;
    }
    __syncthreads();

    const int p = t & 63, og = (t >> 6) * 16;
    float* op = out + ((size_t)b*64 + og)*NPIX + p0 + p;
    #pragma unroll
    for (int kk = 0; kk < 16; ++kk) {
        int o = og + kk;
        float v = (s_t[o*65 + p] - s_mean[o]) * s_rstd[o];
        op[(size_t)kk*NPIX] = (v >= 0.f) ? v : 0.01f*v;
    }
}

extern "C" void kernel_launch(void* const* d_in, const int* in_sizes, int n_in,
                              void* d_out, int out_size, void* d_ws, size_t ws_size,
                              hipStream_t stream) {
    const float* x      = (const float*)d_in[0];
    const float* layout = (const float*)d_in[1];
    const float* pr     = (const float*)d_in[2];
    const float* cw     = (const float*)d_in[3];
    const float* cb     = (const float*)d_in[4];
    const float* Wt     = (const float*)d_in[5];
    const float* bt     = (const float*)d_in[6];
    const float* pl     = (const float*)d_in[7];
    float* out = (float*)d_out;

    char* ws = (char*)d_ws;
    float* sums = (float*)ws;                               // 256 floats (1024 B)
    int*   cnt  = (int*)(ws + 1024);                        // 70 ints (pad to 2048)
    int*   list = (int*)(ws + 2048);                        // 70*CAP ints
    float* xt   = (float*)(ws + 2048 + (size_t)2*NC*CAP*4); // 2*16384*64 floats
    float* yt   = xt + (size_t)2*NPIX*64;

    hipMemsetAsync(d_ws, 0, 2048, stream);                  // zero sums + cnt
    prep_kernel<<<512, 256, 0, stream>>>(x, layout, pr, cw, cb, pl, xt, cnt, list);
    gemm_kernel<<<2*NC*NCHUNK, 256, 0, stream>>>(Wt, bt, xt, cnt, list, yt, sums);
    norm_kernel<<<512, 256, 0, stream>>>(yt, sums, out);
}

// Round 5
// 109.541 us; speedup vs baseline: 1.5999x; 1.5999x over previous
//
#include <hip/hip_runtime.h>

#define HH 128
#define WW 128
#define NPIX (HH*WW)
#define NC 35
#define NB1 512            // prep/scatter blocks (64 px each)
#define NCHK 16            // chunks per bucket
#define CAP (NCHK*64)      // 1024 slots per bucket (actual max ~570)
#define NGB (NC*NCHK)      // 560 gemm blocks per batch
#define NG (2*NGB)         // 1120 total gemm blocks

// ---- K1: transpose x -> xt (+conv scalar), argmax -> argbuf, per-block histogram
__global__ __launch_bounds__(256) void prep_kernel(
    const float* __restrict__ x, const float* __restrict__ layout,
    const float* __restrict__ pr, const float* __restrict__ cw,
    const float* __restrict__ cb, const float* __restrict__ pl,
    float* __restrict__ xt, int* __restrict__ argbuf, int* __restrict__ hist)
{
    __shared__ float s_t[64*65];   // [c][p] stride 65
    __shared__ float s_s[64];
    __shared__ int   s_hist[NC];

    const int t  = threadIdx.x;
    const int bk = blockIdx.x;           // 512: b(2) x ptile(256)
    const int b  = bk >> 8;
    const int p0 = (bk & 255) << 6;
    const int h  = p0 >> 7;
    const int w0 = p0 & 127;

    if (t < NC) s_hist[t] = 0;

    // stage x tile (64c x 64p) into LDS, coalesced float4
    const float4* x4 = (const float4*)x + (size_t)b*64*4096 + (p0 >> 2);
    #pragma unroll
    for (int k = 0; k < 4; ++k) {
        int f = k*256 + t;
        int c = f >> 4, i = f & 15;
        float4 q = x4[c*4096 + i];
        int base = c*65 + i*4;
        s_t[base+0]=q.x; s_t[base+1]=q.y; s_t[base+2]=q.z; s_t[base+3]=q.w;
    }

    int bi = -1;
    if (t < 64) {
        // conv scalar s for pixel p0+t
        int w = w0 + t;
        float pxv = (float)h * (2.0f/128.0f) - 1.0f;
        float pyv = (float)w * (2.0f/128.0f) - 1.0f;
        float pl0 = pl[h*WW + w];
        float pl1 = pl[NPIX + h*WW + w];
        float pr0 = pr[((b*2+0)*HH + h)*WW + w];
        float pr1 = pr[((b*2+1)*HH + h)*WW + w];
        int kx = w % 3, kyy = h % 3;
        const float C1 = -0.5f, S1 = 0.86602540378443864676f;
        float xcv = (kx==0)  ? 1.0f : C1;
        float xsv = (kx==0)  ? 0.0f : ((kx==1)  ? S1 : -S1);
        float ycv = (kyy==0) ? 1.0f : C1;
        float ysv = (kyy==0) ? 0.0f : ((kyy==1) ? S1 : -S1);
        s_s[t] = cb[0] + pxv*cw[0] + pyv*cw[1] + pl0*cw[2] + pl1*cw[3]
               + pr0*cw[4] + pr1*cw[5] + xcv*cw[6] + xsv*cw[7]
               + ycv*cw[8] + ysv*cw[9];
    } else if (t < 128) {
        // argmax (first-max) for pixel p0+lane
        int lane = t - 64;
        const float* lp = layout + (size_t)(b*NC)*NPIX + p0 + lane;
        float best = lp[0]; int bj = 0;
        #pragma unroll
        for (int c = 1; c < NC; ++c) {
            float v = lp[(size_t)c*NPIX];
            if (v > best) { best = v; bj = c; }
        }
        bi = bj;
        argbuf[b*NPIX + p0 + lane] = bj;     // coalesced 256B
    }
    __syncthreads();

    if (bi >= 0) atomicAdd(&s_hist[bi], 1);  // LDS atomic (fast)

    // write xt[b][p][c] = x + s, coalesced 1KB/instr
    float4* xt4 = (float4*)xt + ((size_t)b*NPIX + p0)*16;
    #pragma unroll
    for (int k = 0; k < 4; ++k) {
        int g = k*256 + t;
        int p = g >> 4, c4 = g & 15;
        float sp = s_s[p];
        float4 q;
        q.x = s_t[(c4*4+0)*65 + p] + sp;
        q.y = s_t[(c4*4+1)*65 + p] + sp;
        q.z = s_t[(c4*4+2)*65 + p] + sp;
        q.w = s_t[(c4*4+3)*65 + p] + sp;
        xt4[p*16 + c4] = q;
    }
    __syncthreads();
    if (t < NC) hist[t*NB1 + bk] = s_hist[t];
}

// ---- K2: per-bucket prefix scan of 256 block-histograms -> block offsets + count
__global__ __launch_bounds__(256) void scan_kernel(
    const int* __restrict__ hist, int* __restrict__ boff, int* __restrict__ cnt)
{
    __shared__ int s[256];
    const int e = blockIdx.x;            // 70: e = b*NC + l
    const int b = e / NC, l = e % NC;
    const int t = threadIdx.x;
    int v = hist[l*NB1 + b*256 + t];
    s[t] = v;
    __syncthreads();
    #pragma unroll
    for (int off = 1; off < 256; off <<= 1) {
        int nv = (t >= off) ? s[t-off] : 0;
        __syncthreads();
        s[t] += nv;
        __syncthreads();
    }
    boff[l*NB1 + b*256 + t] = s[t] - v;  // exclusive
    if (t == 255) cnt[e] = s[255];
}

// ---- K3: scatter pixel indices into packed per-bucket lists (LDS-local ranks)
__global__ __launch_bounds__(64) void scatter_kernel(
    const int* __restrict__ argbuf, const int* __restrict__ boff,
    int* __restrict__ list)
{
    __shared__ int s_loc[NC];
    const int t  = threadIdx.x;
    const int bk = blockIdx.x;           // matches prep blocks
    const int b  = bk >> 8;
    const int p0 = (bk & 255) << 6;
    if (t < NC) s_loc[t] = 0;
    __syncthreads();
    int l = argbuf[b*NPIX + p0 + t];
    int r = atomicAdd(&s_loc[l], 1);     // LDS atomic
    int pos = boff[l*NB1 + bk] + r;
    list[(b*NC + l)*CAP + pos] = p0 + t;
}

// ---- K4: bucketed matvec. W_l column in 64 VGPRs/lane (lane=o); x broadcast from LDS.
//      Per-block sum/sumsq partials -> psum/pss (no atomics; inactive blocks write 0).
__global__ __launch_bounds__(256) void gemm_kernel(
    const float* __restrict__ Wt, const float* __restrict__ bt,
    const float* __restrict__ xt, const int* __restrict__ cnt,
    const int* __restrict__ list, float* __restrict__ yt,
    float* __restrict__ psum, float* __restrict__ pss)
{
    const int g     = blockIdx.x;        // b-major: bl = g>>4, bl = b*NC + l
    const int bl    = g >> 4;
    const int chunk = g & (NCHK-1);
    const int t = threadIdx.x, wv = t >> 6, lane = t & 63;
    const int n = cnt[bl];
    const int base = chunk * 64;
    if (base >= n) {
        if (wv == 0) { psum[lane*NG + g] = 0.f; pss[lane*NG + g] = 0.f; }
        return;
    }
    const int m = min(64, n - base);
    const int b = bl / NC, l = bl % NC;

    __shared__ float s_x[64*64];         // [p][c]
    __shared__ int   s_pix[64];
    __shared__ float s_red[4][64][2];

    if (t < 64) s_pix[t] = (t < m) ? list[bl*CAP + base + t] : 0;
    __syncthreads();

    // gather xt rows (256B contiguous each) into LDS
    {
        int p = t >> 2, j = t & 3;
        if (p < m) {
            const float4* r = (const float4*)xt + ((size_t)b*NPIX + s_pix[p])*16;
            #pragma unroll
            for (int k = 0; k < 4; ++k)
                ((float4*)(s_x + p*64 + j*16))[k] = r[j*4 + k];
        }
    }

    // W_l column for this lane -> 64 VGPRs (coalesced 256B loads, L2-hot)
    float Wcol[64];
    const float* Wl = Wt + l*4096 + lane;
    #pragma unroll
    for (int c = 0; c < 64; ++c) Wcol[c] = Wl[c*64];
    float bias = bt[l*64 + lane];
    __syncthreads();

    float ssum = 0.f, sss = 0.f;
    for (int i = 0; i < 16; ++i) {
        int p = wv*16 + i;               // wave-uniform
        if (p < m) {
            float acc = bias;
            const float4* xr = (const float4*)(s_x + p*64);
            #pragma unroll
            for (int c4 = 0; c4 < 16; ++c4) {
                float4 xq = xr[c4];      // all-lane broadcast (free)
                acc = fmaf(xq.x, Wcol[4*c4+0], acc);
                acc = fmaf(xq.y, Wcol[4*c4+1], acc);
                acc = fmaf(xq.z, Wcol[4*c4+2], acc);
                acc = fmaf(xq.w, Wcol[4*c4+3], acc);
            }
            yt[((size_t)b*NPIX + s_pix[p])*64 + lane] = acc;  // 256B coalesced
            ssum += acc; sss += acc*acc;
        }
    }
    s_red[wv][lane][0] = ssum;
    s_red[wv][lane][1] = sss;
    __syncthreads();
    if (wv == 0) {
        float S  = s_red[0][lane][0]+s_red[1][lane][0]+s_red[2][lane][0]+s_red[3][lane][0];
        float SS = s_red[0][lane][1]+s_red[1][lane][1]+s_red[2][lane][1]+s_red[3][lane][1];
        psum[lane*NG + g] = S;
        pss [lane*NG + g] = SS;
    }
}

// ---- K5: reduce 560 partials per (b,o) -> mean & rstd
__global__ __launch_bounds__(256) void stats_kernel(
    const float* __restrict__ psum, const float* __restrict__ pss,
    float* __restrict__ stats)
{
    __shared__ float red[256][2];
    const int e = blockIdx.x;            // 128: b*64 + o
    const int b = e >> 6, o = e & 63;
    const int t = threadIdx.x;
    float S = 0.f, SS = 0.f;
    for (int gl = t; gl < NGB; gl += 256) {
        int g = b*NGB + gl;
        S  += psum[o*NG + g];
        SS += pss [o*NG + g];
    }
    red[t][0] = S; red[t][1] = SS;
    __syncthreads();
    #pragma unroll
    for (int s = 128; s > 0; s >>= 1) {
        if (t < s) { red[t][0] += red[t+s][0]; red[t][1] += red[t+s][1]; }
        __syncthreads();
    }
    if (t == 0) {
        const float invN = 1.0f/16384.0f;
        float mean = red[0][0] * invN;
        float var  = red[0][1] * invN - mean*mean;
        stats[e*2+0] = mean;
        stats[e*2+1] = rsqrtf(var + 1e-5f);
    }
}

// ---- K6: transpose yt -> out with instance-norm + leaky fused
__global__ __launch_bounds__(256) void norm_kernel(
    const float* __restrict__ yt, const float* __restrict__ stats,
    float* __restrict__ out)
{
    __shared__ float s_t[64*65];   // [o][p] stride 65
    __shared__ float s_mean[64], s_rstd[64];

    const int t  = threadIdx.x;
    const int bk = blockIdx.x;           // 512: b x ptile
    const int b  = bk >> 8;
    const int p0 = (bk & 255) << 6;

    if (t < 64) {
        s_mean[t] = stats[(b*64+t)*2+0];
        s_rstd[t] = stats[(b*64+t)*2+1];
    }

    const float4* y4 = (const float4*)yt + ((size_t)b*NPIX + p0)*16;
    #pragma unroll
    for (int k = 0; k < 4; ++k) {
        int g = k*256 + t;
        int p = g >> 4, o4 = g & 15;
        float4 q = y4[p*16 + o4];
        int base = (o4*4)*65 + p;
        s_t[base]     = q.x;
        s_t[base+65]  = q.y;
        s_t[base+130] = q.z;
        s_t[base+195] = q.w;
    }
    __syncthreads();

    const int p = t & 63, og = (t >> 6) * 16;
    float* op = out + ((size_t)b*64 + og)*NPIX + p0 + p;
    #pragma unroll
    for (int kk = 0; kk < 16; ++kk) {
        int o = og + kk;
        float v = (s_t[o*65 + p] - s_mean[o]) * s_rstd[o];
        op[(size_t)kk*NPIX] = (v >= 0.f) ? v : 0.01f*v;
    }
}

extern "C" void kernel_launch(void* const* d_in, const int* in_sizes, int n_in,
                              void* d_out, int out_size, void* d_ws, size_t ws_size,
                              hipStream_t stream) {
    const float* x      = (const float*)d_in[0];
    const float* layout = (const float*)d_in[1];
    const float* pr     = (const float*)d_in[2];
    const float* cw     = (const float*)d_in[3];
    const float* cb     = (const float*)d_in[4];
    const float* Wt     = (const float*)d_in[5];
    const float* bt     = (const float*)d_in[6];
    const float* pl     = (const float*)d_in[7];
    float* out = (float*)d_out;

    char* ws = (char*)d_ws;
    size_t off = 0;
    float* xt     = (float*)(ws + off); off += (size_t)2*NPIX*64*4;        // 8 MB
    float* yt     = (float*)(ws + off); off += (size_t)2*NPIX*64*4;        // 8 MB
    int*   argbuf = (int*)  (ws + off); off += (size_t)2*NPIX*4;           // 128 KB
    int*   hist   = (int*)  (ws + off); off += (size_t)NC*NB1*4;           // 70 KB
    int*   boff   = (int*)  (ws + off); off += (size_t)NC*NB1*4;           // 70 KB
    int*   cnt    = (int*)  (ws + off); off += 512;                        // 128 ints (>= 70!)
    int*   list   = (int*)  (ws + off); off += (size_t)2*NC*CAP*4;         // 280 KB
    float* psum   = (float*)(ws + off); off += (size_t)64*NG*4;            // 280 KB
    float* pss    = (float*)(ws + off); off += (size_t)64*NG*4;            // 280 KB
    float* stats  = (float*)(ws + off); off += 128*2*4;

    prep_kernel   <<<NB1, 256, 0, stream>>>(x, layout, pr, cw, cb, pl, xt, argbuf, hist);
    scan_kernel   <<<2*NC, 256, 0, stream>>>(hist, boff, cnt);
    scatter_kernel<<<NB1,  64, 0, stream>>>(argbuf, boff, list);
    gemm_kernel   <<<NG,  256, 0, stream>>>(Wt, bt, xt, cnt, list, yt, psum, pss);
    stats_kernel  <<<128, 256, 0, stream>>>(psum, pss, stats);
    norm_kernel   <<<NB1, 256, 0, stream>>>(yt, stats, out);
}

// Round 6
// 103.414 us; speedup vs baseline: 1.6947x; 1.0592x over previous
//
#include <hip/hip_runtime.h>

#define HH 128
#define WW 128
#define NPIX (HH*WW)
#define NC 35
#define NB1 512            // prep/norm blocks (64 px each)
#define NWIN 16            // 1024-pixel windows per batch
#define NGB (NC*NWIN)      // 560 gemm blocks per batch
#define NG (2*NGB)         // 1120 total gemm blocks

// ---- K1: transpose x -> xt (pixel-major, +conv scalar), argmax -> argbuf
__global__ __launch_bounds__(256) void prep_kernel(
    const float* __restrict__ x, const float* __restrict__ layout,
    const float* __restrict__ pr, const float* __restrict__ cw,
    const float* __restrict__ cb, const float* __restrict__ pl,
    float* __restrict__ xt, int* __restrict__ argbuf)
{
    __shared__ float s_t[64*65];   // [c][p] stride 65
    __shared__ float s_s[64];

    const int t  = threadIdx.x;
    const int bk = blockIdx.x;           // 512: b(2) x ptile(256)
    const int b  = bk >> 8;
    const int p0 = (bk & 255) << 6;
    const int h  = p0 >> 7;
    const int w0 = p0 & 127;

    // stage x tile (64c x 64p) into LDS, coalesced float4
    const float4* x4 = (const float4*)x + (size_t)b*64*4096 + (p0 >> 2);
    #pragma unroll
    for (int k = 0; k < 4; ++k) {
        int f = k*256 + t;
        int c = f >> 4, i = f & 15;
        float4 q = x4[c*4096 + i];
        int base = c*65 + i*4;
        s_t[base+0]=q.x; s_t[base+1]=q.y; s_t[base+2]=q.z; s_t[base+3]=q.w;
    }

    if (t < 64) {
        // conv scalar s for pixel p0+t
        int w = w0 + t;
        float pxv = (float)h * (2.0f/128.0f) - 1.0f;
        float pyv = (float)w * (2.0f/128.0f) - 1.0f;
        float pl0 = pl[h*WW + w];
        float pl1 = pl[NPIX + h*WW + w];
        float pr0 = pr[((b*2+0)*HH + h)*WW + w];
        float pr1 = pr[((b*2+1)*HH + h)*WW + w];
        int kx = w % 3, kyy = h % 3;
        const float C1 = -0.5f, S1 = 0.86602540378443864676f;
        float xcv = (kx==0)  ? 1.0f : C1;
        float xsv = (kx==0)  ? 0.0f : ((kx==1)  ? S1 : -S1);
        float ycv = (kyy==0) ? 1.0f : C1;
        float ysv = (kyy==0) ? 0.0f : ((kyy==1) ? S1 : -S1);
        s_s[t] = cb[0] + pxv*cw[0] + pyv*cw[1] + pl0*cw[2] + pl1*cw[3]
               + pr0*cw[4] + pr1*cw[5] + xcv*cw[6] + xsv*cw[7]
               + ycv*cw[8] + ysv*cw[9];
    } else if (t < 128) {
        // argmax (first-max) for pixel p0+lane
        int lane = t - 64;
        const float* lp = layout + (size_t)(b*NC)*NPIX + p0 + lane;
        float best = lp[0]; int bj = 0;
        #pragma unroll
        for (int c = 1; c < NC; ++c) {
            float v = lp[(size_t)c*NPIX];
            if (v > best) { best = v; bj = c; }
        }
        argbuf[b*NPIX + p0 + lane] = bj;     // coalesced 256B
    }
    __syncthreads();

    // write xt[b][p][c] = x + s, coalesced 1KB/instr
    float4* xt4 = (float4*)xt + ((size_t)b*NPIX + p0)*16;
    #pragma unroll
    for (int k = 0; k < 4; ++k) {
        int g = k*256 + t;
        int p = g >> 4, c4 = g & 15;
        float sp = s_s[p];
        float4 q;
        q.x = s_t[(c4*4+0)*65 + p] + sp;
        q.y = s_t[(c4*4+1)*65 + p] + sp;
        q.z = s_t[(c4*4+2)*65 + p] + sp;
        q.w = s_t[(c4*4+3)*65 + p] + sp;
        xt4[p*16 + c4] = q;
    }
}

// ---- K2: self-selecting bucketed matvec. Block = (b, label, 1024-px window).
//      Ballot-compacts matching pixels into LDS, W_l column in 64 VGPRs/lane.
__global__ __launch_bounds__(256) void gemm_kernel(
    const float* __restrict__ Wt, const float* __restrict__ bt,
    const float* __restrict__ xt, const int* __restrict__ argbuf,
    float* __restrict__ yt, float* __restrict__ psum, float* __restrict__ pss)
{
    const int g   = blockIdx.x;          // b-major
    const int b   = g / NGB;
    const int rem = g % NGB;
    const int l   = rem >> 4;
    const int win = rem & (NWIN-1);
    const int t = threadIdx.x, wv = t >> 6, lane = t & 63;

    __shared__ int   s_list[1024];
    __shared__ int   s_n;
    __shared__ float s_x[64*64];         // [p][c]
    __shared__ float s_red[4][64][2];

    if (t == 0) s_n = 0;
    __syncthreads();

    // ---- ballot compaction of this window's matches (order-free) ----
    const int wpix = win*1024;
    #pragma unroll
    for (int j = 0; j < 4; ++j) {
        int idx = wv*256 + j*64 + lane;
        int a = argbuf[b*NPIX + wpix + idx];
        bool match = (a == l);
        unsigned long long mask = __ballot(match);
        int total = __popcll(mask);
        if (total) {
            int base = 0;
            if (lane == 0) base = atomicAdd(&s_n, total);
            base = __shfl(base, 0);
            if (match) {
                int rank = __popcll(mask & ((1ull << lane) - 1ull));
                s_list[base + rank] = wpix + idx;
            }
        }
    }

    // ---- W_l column for this lane -> 64 VGPRs (sequential 16KB, L2-hot) ----
    float Wcol[64];
    const float* Wl = Wt + l*4096 + lane;
    #pragma unroll
    for (int c = 0; c < 64; ++c) Wcol[c] = Wl[c*64];
    float bias = bt[l*64 + lane];
    __syncthreads();
    const int m = s_n;

    float ssum = 0.f, sss = 0.f;
    for (int base0 = 0; base0 < m; base0 += 64) {
        int mm = min(64, m - base0);
        // stage matched xt rows (256B contiguous each) into LDS
        {
            int p = t >> 2, j = t & 3;
            if (p < mm) {
                const float4* r = (const float4*)xt + ((size_t)b*NPIX + s_list[base0+p])*16;
                #pragma unroll
                for (int k = 0; k < 4; ++k)
                    ((float4*)(s_x + p*64 + j*16))[k] = r[j*4 + k];
            }
        }
        __syncthreads();
        for (int i = wv; i < mm; i += 4) {
            const float4* xr = (const float4*)(s_x + i*64);
            float a0 = bias, a1 = 0.f, a2 = 0.f, a3 = 0.f;
            #pragma unroll
            for (int c4 = 0; c4 < 16; c4 += 4) {
                float4 q0 = xr[c4+0], q1 = xr[c4+1], q2 = xr[c4+2], q3 = xr[c4+3];
                a0 = fmaf(q0.x, Wcol[4*c4+ 0], a0); a0 = fmaf(q0.y, Wcol[4*c4+ 1], a0);
                a0 = fmaf(q0.z, Wcol[4*c4+ 2], a0); a0 = fmaf(q0.w, Wcol[4*c4+ 3], a0);
                a1 = fmaf(q1.x, Wcol[4*c4+ 4], a1); a1 = fmaf(q1.y, Wcol[4*c4+ 5], a1);
                a1 = fmaf(q1.z, Wcol[4*c4+ 6], a1); a1 = fmaf(q1.w, Wcol[4*c4+ 7], a1);
                a2 = fmaf(q2.x, Wcol[4*c4+ 8], a2); a2 = fmaf(q2.y, Wcol[4*c4+ 9], a2);
                a2 = fmaf(q2.z, Wcol[4*c4+10], a2); a2 = fmaf(q2.w, Wcol[4*c4+11], a2);
                a3 = fmaf(q3.x, Wcol[4*c4+12], a3); a3 = fmaf(q3.y, Wcol[4*c4+13], a3);
                a3 = fmaf(q3.z, Wcol[4*c4+14], a3); a3 = fmaf(q3.w, Wcol[4*c4+15], a3);
            }
            float acc = (a0 + a1) + (a2 + a3);
            yt[((size_t)b*NPIX + s_list[base0+i])*64 + lane] = acc;  // 256B coalesced
            ssum += acc; sss += acc*acc;
        }
        __syncthreads();   // protect s_x before next stage
    }

    s_red[wv][lane][0] = ssum;
    s_red[wv][lane][1] = sss;
    __syncthreads();
    if (wv == 0) {
        float S  = s_red[0][lane][0]+s_red[1][lane][0]+s_red[2][lane][0]+s_red[3][lane][0];
        float SS = s_red[0][lane][1]+s_red[1][lane][1]+s_red[2][lane][1]+s_red[3][lane][1];
        psum[g*64 + lane] = S;      // coalesced
        pss [g*64 + lane] = SS;
    }
}

// ---- K3: reduce 560 partials per (b,o) -> mean & rstd
__global__ __launch_bounds__(256) void stats_kernel(
    const float* __restrict__ psum, const float* __restrict__ pss,
    float* __restrict__ stats)
{
    __shared__ float red[256][2];
    const int e = blockIdx.x;            // 128: b*64 + o
    const int b = e >> 6, o = e & 63;
    const int t = threadIdx.x;
    float S = 0.f, SS = 0.f;
    for (int gl = t; gl < NGB; gl += 256) {
        int g = b*NGB + gl;
        S  += psum[g*64 + o];
        SS += pss [g*64 + o];
    }
    red[t][0] = S; red[t][1] = SS;
    __syncthreads();
    #pragma unroll
    for (int s = 128; s > 0; s >>= 1) {
        if (t < s) { red[t][0] += red[t+s][0]; red[t][1] += red[t+s][1]; }
        __syncthreads();
    }
    if (t == 0) {
        const float invN = 1.0f/16384.0f;
        float mean = red[0][0] * invN;
        float var  = red[0][1] * invN - mean*mean;
        stats[e*2+0] = mean;
        stats[e*2+1] = rsqrtf(var + 1e-5f);
    }
}

// ---- K4: transpose yt -> out with instance-norm + leaky fused
__global__ __launch_bounds__(256) void norm_kernel(
    const float* __restrict__ yt, const float* __restrict__ stats,
    float* __restrict__ out)
{
    __shared__ float s_t[64*65];   // [o][p] stride 65
    __shared__ float s_mean[64], s_rstd[64];

    const int t  = threadIdx.x;
    const int bk = blockIdx.x;           // 512: b x ptile
    const int b  = bk >> 8;
    const int p0 = (bk & 255) << 6;

    if (t < 64) {
        s_mean[t] = stats[(b*64+t)*2+0];
        s_rstd[t] = stats[(b*64+t)*2+1];
    }

    const float4* y4 = (const float4*)yt + ((size_t)b*NPIX + p0)*16;
    #pragma unroll
    for (int k = 0; k < 4; ++k) {
        int g = k*256 + t;
        int p = g >> 4, o4 = g & 15;
        float4 q = y4[p*16 + o4];
        int base = (o4*4)*65 + p;
        s_t[base]     = q.x;
        s_t[base+65]  = q.y;
        s_t[base+130] = q.z;
        s_t[base+195] = q.w;
    }
    __syncthreads();

    const int p = t & 63, og = (t >> 6) * 16;
    float* op = out + ((size_t)b*64 + og)*NPIX + p0 + p;
    #pragma unroll
    for (int kk = 0; kk < 16; ++kk) {
        int o = og + kk;
        float v = (s_t[o*65 + p] - s_mean[o]) * s_rstd[o];
        op[(size_t)kk*NPIX] = (v >= 0.f) ? v : 0.01f*v;
    }
}

extern "C" void kernel_launch(void* const* d_in, const int* in_sizes, int n_in,
                              void* d_out, int out_size, void* d_ws, size_t ws_size,
                              hipStream_t stream) {
    const float* x      = (const float*)d_in[0];
    const float* layout = (const float*)d_in[1];
    const float* pr     = (const float*)d_in[2];
    const float* cw     = (const float*)d_in[3];
    const float* cb     = (const float*)d_in[4];
    const float* Wt     = (const float*)d_in[5];
    const float* bt     = (const float*)d_in[6];
    const float* pl     = (const float*)d_in[7];
    float* out = (float*)d_out;

    char* ws = (char*)d_ws;
    size_t off = 0;
    float* xt     = (float*)(ws + off); off += (size_t)2*NPIX*64*4;   // 8 MB
    float* yt     = (float*)(ws + off); off += (size_t)2*NPIX*64*4;   // 8 MB
    int*   argbuf = (int*)  (ws + off); off += (size_t)2*NPIX*4;      // 128 KB
    float* psum   = (float*)(ws + off); off += (size_t)NG*64*4;       // 280 KB
    float* pss    = (float*)(ws + off); off += (size_t)NG*64*4;       // 280 KB
    float* stats  = (float*)(ws + off); off += 128*2*4;

    prep_kernel <<<NB1, 256, 0, stream>>>(x, layout, pr, cw, cb, pl, xt, argbuf);
    gemm_kernel <<<NG,  256, 0, stream>>>(Wt, bt, xt, argbuf, yt, psum, pss);
    stats_kernel<<<128, 256, 0, stream>>>(psum, pss, stats);
    norm_kernel <<<NB1, 256, 0, stream>>>(yt, stats, out);
}